// Round 10
// baseline (128.536 us; speedup 1.0000x reference)
//
#include <hip/hip_runtime.h>
#include <hip/hip_bf16.h>
#include <hip/hip_cooperative_groups.h>
#include <math.h>

namespace cg = cooperative_groups;

#define NB 32
#define NL 128
#define ND 128

typedef __attribute__((ext_vector_type(8))) short bf16x8;
typedef __attribute__((ext_vector_type(4))) float f32x4;

union F4  { float4 v; float f[4]; };
union BF8 { bf16x8 v; ushort u[8]; };

__device__ inline ushort f2bf(float f) {
    __hip_bfloat16 h = __float2bfloat16(f);
    union { __hip_bfloat16 h; ushort u; } c; c.h = h; return c.u;
}
__device__ inline float bf2f(ushort u) {
    union { unsigned int i; float f; } c; c.i = ((unsigned int)u) << 16; return c.f;
}
__device__ inline short2 bsplit(float f) {
    ushort hu = f2bf(f);
    short2 r;
    r.x = (short)hu;
    r.y = (short)f2bf(f - bf2f(hu));
    return r;
}

// ---------------------------------------------------------------------------
// k_coop: single cooperative kernel, grid 256 x 256 threads (1 block/CU).
// Phase 0: pre-split W -> whg/wlg bf16 hi/lo [mat][d][k].          grid.sync
// Phase 1 (block = b x 16-row l-tile): proj split-bf16 MFMA
//   (A = X from global + in-reg split; B = pre-split W, L2). acc[4 mat][2 nt]
//   = 32 VGPR. Epilogue: logits -> lgG[c][b][l]; y2/y3 bf16 -> gtb[arr][b][d][l].
//                                                                  grid.sync
// Phase 2 (block = b x {term,dq,eo}): wave-parallel softmax; stage G (64 KB
//   LDS, XOR-swizzled, r8-verified layout); gram MFMA with in-register
//   A-scale (r9-verified): Mr = (wr.r2)r2^T - (wr.i2)i2^T ;
//   Mi = (wi.i2)r2^T + (wi.r2)i2^T. fp32 C-write (r4-verified mapping).
// LDS: 64K G + wfl 512B + wred 64B (phase-1 overlays lgpart at 0).
// ---------------------------------------------------------------------------
__global__ __launch_bounds__(256, 1) void k_coop(
    const float* __restrict__ xr, const float* __restrict__ xi,
    const float* __restrict__ Wr1, const float* __restrict__ br1,
    const float* __restrict__ Wi1, const float* __restrict__ bi1,
    const float* __restrict__ Wr2, const float* __restrict__ br2,
    const float* __restrict__ Wi2, const float* __restrict__ bi2,
    ushort* __restrict__ whg, ushort* __restrict__ wlg,
    ushort* __restrict__ gtb, float* __restrict__ lgG,
    float* __restrict__ out)
{
    extern __shared__ char L[];
    float* lgpart = (float*)L;             // phase 1: [2 c][4 w][16 row]
    float* wfl    = (float*)(L + 65536);   // phase 2: 128 weights
    float* wred   = (float*)(L + 66048);   // cross-wave scratch

    const int bid   = blockIdx.x;
    const int t     = threadIdx.x;
    const int w     = t >> 6;
    const int lane  = t & 63;
    const int l15   = lane & 15;
    const int koff8 = (lane >> 4) * 8;
    const int koffb = koff8 * 2;

    cg::grid_group grid = cg::this_grid();

    // ================= phase 0: W pre-split =================
    {
        int tg = bid * 256 + t;
        if (tg < 16384) {
            int mat    = tg >> 12;
            int within = (tg & 4095) * 4;
            const float* W = (mat == 0) ? Wr1 : (mat == 1) ? Wi1
                           : (mat == 2) ? Wr2 : Wi2;
            F4 v; v.v = *(const float4*)&W[within];
            short2 s0 = bsplit(v.f[0]), s1 = bsplit(v.f[1]);
            short2 s2 = bsplit(v.f[2]), s3 = bsplit(v.f[3]);
            ushort4 h = {(ushort)s0.x, (ushort)s1.x, (ushort)s2.x, (ushort)s3.x};
            ushort4 l = {(ushort)s0.y, (ushort)s1.y, (ushort)s2.y, (ushort)s3.y};
            *(ushort4*)&whg[mat * 16384 + within] = h;
            *(ushort4*)&wlg[mat * 16384 + within] = l;
        }
    }
    __threadfence();
    grid.sync();

    // ================= phase 1: proj + logits + G =================
    {
        const int b  = bid >> 3;
        const int lt = bid & 7;
        const int arowg = b * NL + lt * 16 + l15;   // global X row

        // A-fragments: X fp32 from global, split in-reg
        bf16x8 axh[2][4], axl[2][4];
        {
            const float* xs[2] = {xr, xi};
#pragma unroll
            for (int arr = 0; arr < 2; ++arr)
#pragma unroll
                for (int ks = 0; ks < 4; ++ks) {
                    const float* p = xs[arr] + (size_t)arowg * ND + ks * 32 + koff8;
                    F4 f0, f1;
                    f0.v = *(const float4*)&p[0];
                    f1.v = *(const float4*)&p[4];
                    bf16x8 h, l;
#pragma unroll
                    for (int e = 0; e < 4; ++e) {
                        short2 s = bsplit(f0.f[e]); h[e] = s.x; l[e] = s.y;
                    }
#pragma unroll
                    for (int e = 0; e < 4; ++e) {
                        short2 s = bsplit(f1.f[e]); h[4 + e] = s.x; l[4 + e] = s.y;
                    }
                    axh[arr][ks] = h;
                    axl[arr][ks] = l;
                }
        }

        // proj MFMA: wave w covers n-tiles w*2, w*2+1
        f32x4 acc[4][2];
#pragma unroll
        for (int m = 0; m < 4; ++m)
#pragma unroll
            for (int n = 0; n < 2; ++n) acc[m][n] = (f32x4){0.f, 0.f, 0.f, 0.f};

#pragma unroll
        for (int mat = 0; mat < 4; ++mat) {
            const int arr = mat & 1;
#pragma unroll
            for (int n = 0; n < 2; ++n) {
                const int nt = w * 2 + n;
                const ushort* wp = whg + mat * 16384 + (nt * 16 + l15) * 128 + koff8;
                const ushort* lp = wlg + mat * 16384 + (nt * 16 + l15) * 128 + koff8;
#pragma unroll
                for (int ks = 0; ks < 4; ++ks) {
                    bf16x8 bh = *(const bf16x8*)&wp[ks * 32];
                    bf16x8 bl = *(const bf16x8*)&lp[ks * 32];
                    acc[mat][n] = __builtin_amdgcn_mfma_f32_16x16x32_bf16(axh[arr][ks], bh, acc[mat][n], 0, 0, 0);
                    acc[mat][n] = __builtin_amdgcn_mfma_f32_16x16x32_bf16(axh[arr][ks], bl, acc[mat][n], 0, 0, 0);
                    acc[mat][n] = __builtin_amdgcn_mfma_f32_16x16x32_bf16(axl[arr][ks], bh, acc[mat][n], 0, 0, 0);
                }
            }
        }

        // epilogue: bias, partial logits, G writes
        float pR[4] = {0.f, 0.f, 0.f, 0.f};
        float pI[4] = {0.f, 0.f, 0.f, 0.f};
        const int lbase = lt * 16 + (lane >> 4) * 4;
#pragma unroll
        for (int n = 0; n < 2; ++n) {
            const int d = (w * 2 + n) * 16 + l15;
            const float b0 = br1[d], b1 = bi1[d], b2 = br2[d], b3 = bi2[d];
            ushort g2[4], g3[4];
#pragma unroll
            for (int r = 0; r < 4; ++r) {
                float y0 = acc[0][n][r] + b0;
                float y1 = acc[1][n][r] + b1;
                float y2 = acc[2][n][r] + b2;
                float y3 = acc[3][n][r] + b3;
                pR[r] += (y0 * y0 - y1 * y1) * (y2 * y2 - y3 * y3);
                pI[r] += 4.f * y0 * y1 * y2 * y3;
                g2[r] = f2bf(y2);
                g3[r] = f2bf(y3);
            }
            ushort4 q2 = {g2[0], g2[1], g2[2], g2[3]};
            ushort4 q3 = {g3[0], g3[1], g3[2], g3[3]};
            *(ushort4*)&gtb[((size_t)(0 * NB + b) * ND + d) * NL + lbase] = q2;
            *(ushort4*)&gtb[((size_t)(1 * NB + b) * ND + d) * NL + lbase] = q3;
        }

#pragma unroll
        for (int off = 1; off < 16; off <<= 1)
#pragma unroll
            for (int r = 0; r < 4; ++r) {
                pR[r] += __shfl_xor(pR[r], off);
                pI[r] += __shfl_xor(pI[r], off);
            }
        if (l15 == 0) {
            const int row = (lane >> 4) * 4;
#pragma unroll
            for (int r = 0; r < 4; ++r) {
                lgpart[(0 * 4 + w) * 16 + row + r] = pR[r];
                lgpart[(1 * 4 + w) * 16 + row + r] = pI[r];
            }
        }
        __syncthreads();
        if (t < 32) {
            const int c = t >> 4, row = t & 15;
            float s = lgpart[(c * 4 + 0) * 16 + row] + lgpart[(c * 4 + 1) * 16 + row]
                    + lgpart[(c * 4 + 2) * 16 + row] + lgpart[(c * 4 + 3) * 16 + row];
            lgG[(size_t)(c * NB + b) * NL + lt * 16 + row] = s;
        }
    }
    __threadfence();
    grid.sync();

    // ================= phase 2: softmax + gram =================
    {
        const int b    = bid >> 3;
        const int sub  = bid & 7;
        const int term = sub >> 2;
        const int dq   = (sub >> 1) & 1;
        const int eo   = sub & 1;

        // wave-parallel softmax (waves 0,1)
        float sv = 0.f, se = 0.f;
        if (t < 128) {
            sv = lgG[(size_t)(term * NB + b) * NL + t];
            float m = sv;
#pragma unroll
            for (int off = 1; off < 64; off <<= 1) m = fmaxf(m, __shfl_xor(m, off));
            if (lane == 0) wred[w] = m;
        }
        __syncthreads();
        if (t < 128) {
            float m = fmaxf(wred[0], wred[1]);
            se = expf(sv - m);
            float s = se;
#pragma unroll
            for (int off = 1; off < 64; off <<= 1) s += __shfl_xor(s, off);
            if (lane == 0) wred[2 + w] = s;
        }
        __syncthreads();
        if (t < 128) wfl[t] = se / (wred[2] + wred[3]);

        // stage full G of batch b (both arrays, 128 rows), swizzled
#pragma unroll
        for (int j = 0; j < 16; ++j) {
            int u    = t + 256 * j;
            int arr  = u >> 11;
            int row  = (u >> 4) & 127;
            int slot = u & 15;
            bf16x8 v = *(const bf16x8*)&gtb[((size_t)(arr * NB + b) * ND + row) * NL + slot * 8];
            *(bf16x8*)(L + arr * 32768 + row * 256 + ((slot * 16) ^ ((row & 7) << 4))) = v;
        }
        __syncthreads();   // covers staging AND wfl writes

        // gram MFMA: wave = m-tile w of M-half dq; nt over N-half eo
        f32x4 accP[4], accN[4];
#pragma unroll
        for (int nt = 0; nt < 4; ++nt) {
            accP[nt] = (f32x4){0.f, 0.f, 0.f, 0.f};
            accN[nt] = (f32x4){0.f, 0.f, 0.f, 0.f};
        }

#pragma unroll
        for (int ks = 0; ks < 4; ++ks) {
            F4 w0, w1;
            w0.v = *(const float4*)&wfl[ks * 32 + koff8];
            w1.v = *(const float4*)&wfl[ks * 32 + koff8 + 4];
            float wv[8] = {w0.f[0], w0.f[1], w0.f[2], w0.f[3],
                           w1.f[0], w1.f[1], w1.f[2], w1.f[3]};

            const int ar = dq * 64 + w * 16 + l15;
            const int ab = ar * 256 + (((ks * 64) + koffb) ^ ((ar & 7) << 4));
            BF8 a0; a0.v = *(const bf16x8*)(L + ab);
            BF8 a1; a1.v = *(const bf16x8*)(L + 32768 + ab);
            bf16x8 s0, s1;
#pragma unroll
            for (int e = 0; e < 8; ++e) {
                s0[e] = (short)f2bf(bf2f(a0.u[e]) * wv[e]);
                s1[e] = (short)f2bf(bf2f(a1.u[e]) * wv[e]);
            }
            bf16x8 aP = term ? s1 : s0;   // R: wr.r2 ; I: wi.i2
            bf16x8 aN = term ? s0 : s1;   // R: wr.i2 ; I: wi.r2

#pragma unroll
            for (int nt = 0; nt < 4; ++nt) {
                const int br = eo * 64 + nt * 16 + l15;
                const int bb = br * 256 + (((ks * 64) + koffb) ^ ((br & 7) << 4));
                bf16x8 b0 = *(const bf16x8*)(L + bb);
                bf16x8 b1 = *(const bf16x8*)(L + 32768 + bb);
                accP[nt] = __builtin_amdgcn_mfma_f32_16x16x32_bf16(aP, b0, accP[nt], 0, 0, 0);
                accN[nt] = __builtin_amdgcn_mfma_f32_16x16x32_bf16(aN, b1, accN[nt], 0, 0, 0);
            }
        }

        const float sgn = term ? 1.f : -1.f;
        float* dst = out + (size_t)term * NB * ND * ND + (size_t)b * ND * ND;
        const int rb = dq * 64 + w * 16 + (lane >> 4) * 4;
#pragma unroll
        for (int nt = 0; nt < 4; ++nt) {
            const int ec = eo * 64 + nt * 16 + l15;
#pragma unroll
            for (int r = 0; r < 4; ++r)
                dst[(size_t)(rb + r) * ND + ec] = accP[nt][r] + sgn * accN[nt][r];
        }
    }
}

extern "C" void kernel_launch(void* const* d_in, const int* in_sizes, int n_in,
                              void* d_out, int out_size, void* d_ws, size_t ws_size,
                              hipStream_t stream)
{
    const float* xr  = (const float*)d_in[0];
    const float* xi  = (const float*)d_in[1];
    const float* Wr1 = (const float*)d_in[2];
    const float* br1 = (const float*)d_in[3];
    const float* Wi1 = (const float*)d_in[4];
    const float* bi1 = (const float*)d_in[5];
    const float* Wr2 = (const float*)d_in[6];
    const float* br2 = (const float*)d_in[7];
    const float* Wi2 = (const float*)d_in[8];
    const float* bi2 = (const float*)d_in[9];

    ushort* whg = (ushort*)d_ws;                 // [4][128][128] bf16 hi
    ushort* wlg = whg + 4 * 16384;               // [4][128][128] bf16 lo
    ushort* gtb = wlg + 4 * 16384;               // [2][b][d][l] bf16
    float*  lgG = (float*)(gtb + 2 * NB * ND * NL);  // [2][b][l]
    float*  out = (float*)d_out;

    (void)hipFuncSetAttribute((const void*)k_coop,
                              hipFuncAttributeMaxDynamicSharedMemorySize, 66560);

    void* args[] = {
        (void*)&xr, (void*)&xi,
        (void*)&Wr1, (void*)&br1, (void*)&Wi1, (void*)&bi1,
        (void*)&Wr2, (void*)&br2, (void*)&Wi2, (void*)&bi2,
        (void*)&whg, (void*)&wlg, (void*)&gtb, (void*)&lgG,
        (void*)&out
    };
    (void)hipLaunchCooperativeKernel((const void*)k_coop, dim3(256), dim3(256),
                                     args, 66560, stream);
}

// Round 11
// 25.256 us; speedup vs baseline: 5.0893x; 5.0893x over previous
//
#include <hip/hip_runtime.h>
#include <hip/hip_bf16.h>
#include <math.h>

#define NB 32
#define NL 128
#define ND 128

typedef __attribute__((ext_vector_type(8))) short bf16x8;
typedef __attribute__((ext_vector_type(4))) float f32x4;

union F4  { float4 v; float f[4]; };
union BF8 { bf16x8 v; ushort u[8]; };

__device__ inline ushort f2bf(float f) {
    __hip_bfloat16 h = __float2bfloat16(f);
    union { __hip_bfloat16 h; ushort u; } c; c.h = h; return c.u;
}
__device__ inline float bf2f(ushort u) {
    union { unsigned int i; float f; } c; c.i = ((unsigned int)u) << 16; return c.f;
}
__device__ inline short2 bsplit(float f) {
    ushort hu = f2bf(f);
    short2 r;
    r.x = (short)hu;
    r.y = (short)f2bf(f - bf2f(hu));
    return r;
}

// ---------------------------------------------------------------------------
// k_proj: grid 256 = b(32) x l-tile(8 of 16 rows). Block 256 (4 waves).
// Wave w covers n-tiles {2w, 2w+1} (32 d). acc[4 mats][2] = 32 VGPR.
// A = X fp32 from global + in-reg bsplit (HW-verified ABt fragment pattern).
// B = W fp32 from global (L2-hot, block-uniform) + in-reg bsplit.
// Split-bf16 MFMA: XhWh + XhWl + XlWh (r6-verified).
// Epilogue: bias; logits (16-lane shfl + cross-wave LDS reduce) -> lgG;
// y2/y3 bf16 -> gtb[arr][b][d][l] (r10-phase1-verified, which passed).
// ---------------------------------------------------------------------------
__global__ __launch_bounds__(256) void k_proj(
    const float* __restrict__ xr, const float* __restrict__ xi,
    const float* __restrict__ Wr1, const float* __restrict__ br1,
    const float* __restrict__ Wi1, const float* __restrict__ bi1,
    const float* __restrict__ Wr2, const float* __restrict__ br2,
    const float* __restrict__ Wi2, const float* __restrict__ bi2,
    ushort* __restrict__ gtb, float* __restrict__ lgG)
{
    __shared__ float lgpart[2 * 4 * 16];   // [c][wave][row]

    const int bid   = blockIdx.x;
    const int t     = threadIdx.x;
    const int w     = t >> 6;
    const int lane  = t & 63;
    const int l15   = lane & 15;
    const int koff8 = (lane >> 4) * 8;
    const int b     = bid >> 3;
    const int lt    = bid & 7;
    const int arowg = b * NL + lt * 16 + l15;

    // ---- A-fragments: X fp32 -> in-reg split ----
    bf16x8 axh[2][4], axl[2][4];
    {
        const float* xs[2] = {xr, xi};
#pragma unroll
        for (int arr = 0; arr < 2; ++arr)
#pragma unroll
            for (int ks = 0; ks < 4; ++ks) {
                const float* p = xs[arr] + (size_t)arowg * ND + ks * 32 + koff8;
                F4 f0, f1;
                f0.v = *(const float4*)&p[0];
                f1.v = *(const float4*)&p[4];
                bf16x8 h, l;
#pragma unroll
                for (int e = 0; e < 4; ++e) {
                    short2 s = bsplit(f0.f[e]); h[e] = s.x; l[e] = s.y;
                }
#pragma unroll
                for (int e = 0; e < 4; ++e) {
                    short2 s = bsplit(f1.f[e]); h[4 + e] = s.x; l[4 + e] = s.y;
                }
                axh[arr][ks] = h;
                axl[arr][ks] = l;
            }
    }

    // ---- proj MFMA: B-frags straight from W fp32 (L2) + in-reg split ----
    f32x4 acc[4][2];
#pragma unroll
    for (int m = 0; m < 4; ++m)
#pragma unroll
        for (int n = 0; n < 2; ++n) acc[m][n] = (f32x4){0.f, 0.f, 0.f, 0.f};

    {
        const float* Ws[4] = {Wr1, Wi1, Wr2, Wi2};
#pragma unroll
        for (int mat = 0; mat < 4; ++mat) {
            const int arr = mat & 1;
#pragma unroll
            for (int n = 0; n < 2; ++n) {
                const float* wrow = Ws[mat] + (size_t)((w * 2 + n) * 16 + l15) * ND;
#pragma unroll
                for (int ks = 0; ks < 4; ++ks) {
                    F4 f0, f1;
                    f0.v = *(const float4*)&wrow[ks * 32 + koff8];
                    f1.v = *(const float4*)&wrow[ks * 32 + koff8 + 4];
                    bf16x8 bh, bl;
#pragma unroll
                    for (int e = 0; e < 4; ++e) {
                        short2 s = bsplit(f0.f[e]); bh[e] = s.x; bl[e] = s.y;
                    }
#pragma unroll
                    for (int e = 0; e < 4; ++e) {
                        short2 s = bsplit(f1.f[e]); bh[4 + e] = s.x; bl[4 + e] = s.y;
                    }
                    acc[mat][n] = __builtin_amdgcn_mfma_f32_16x16x32_bf16(axh[arr][ks], bh, acc[mat][n], 0, 0, 0);
                    acc[mat][n] = __builtin_amdgcn_mfma_f32_16x16x32_bf16(axh[arr][ks], bl, acc[mat][n], 0, 0, 0);
                    acc[mat][n] = __builtin_amdgcn_mfma_f32_16x16x32_bf16(axl[arr][ks], bh, acc[mat][n], 0, 0, 0);
                }
            }
        }
    }

    // ---- epilogue: bias, partial logits, G writes ----
    float pR[4] = {0.f, 0.f, 0.f, 0.f};
    float pI[4] = {0.f, 0.f, 0.f, 0.f};
    const int lbase = lt * 16 + (lane >> 4) * 4;
#pragma unroll
    for (int n = 0; n < 2; ++n) {
        const int d = (w * 2 + n) * 16 + l15;
        const float b0 = br1[d], b1 = bi1[d], b2 = br2[d], b3 = bi2[d];
        ushort g2[4], g3[4];
#pragma unroll
        for (int r = 0; r < 4; ++r) {
            float y0 = acc[0][n][r] + b0;
            float y1 = acc[1][n][r] + b1;
            float y2 = acc[2][n][r] + b2;
            float y3 = acc[3][n][r] + b3;
            pR[r] += (y0 * y0 - y1 * y1) * (y2 * y2 - y3 * y3);
            pI[r] += 4.f * y0 * y1 * y2 * y3;
            g2[r] = f2bf(y2);
            g3[r] = f2bf(y3);
        }
        ushort4 q2 = {g2[0], g2[1], g2[2], g2[3]};
        ushort4 q3 = {g3[0], g3[1], g3[2], g3[3]};
        *(ushort4*)&gtb[((size_t)(0 * NB + b) * ND + d) * NL + lbase] = q2;
        *(ushort4*)&gtb[((size_t)(1 * NB + b) * ND + d) * NL + lbase] = q3;
    }

#pragma unroll
    for (int off = 1; off < 16; off <<= 1)
#pragma unroll
        for (int r = 0; r < 4; ++r) {
            pR[r] += __shfl_xor(pR[r], off);
            pI[r] += __shfl_xor(pI[r], off);
        }
    if (l15 == 0) {
        const int row = (lane >> 4) * 4;
#pragma unroll
        for (int r = 0; r < 4; ++r) {
            lgpart[(0 * 4 + w) * 16 + row + r] = pR[r];
            lgpart[(1 * 4 + w) * 16 + row + r] = pI[r];
        }
    }
    __syncthreads();
    if (t < 32) {
        const int c = t >> 4, row = t & 15;
        float s = lgpart[(c * 4 + 0) * 16 + row] + lgpart[(c * 4 + 1) * 16 + row]
                + lgpart[(c * 4 + 2) * 16 + row] + lgpart[(c * 4 + 3) * 16 + row];
        lgG[(size_t)(c * NB + b) * NL + lt * 16 + row] = s;
    }
}

// ---------------------------------------------------------------------------
// k_gram: grid 256 = b(32) x {term, dq, eo}(8). Block 256 (4 waves).
// Wave-parallel softmax (redundant per block) -> wfl; stage G (64 KB LDS,
// XOR-swizzled, r8-verified); gram MFMA with in-register A-scale
// (r9/r10-verified): Mr = (wr.r2)r2^T - (wr.i2)i2^T ;
//                    Mi = (wi.i2)r2^T + (wi.r2)i2^T.
// ---------------------------------------------------------------------------
__global__ __launch_bounds__(256) void k_gram(
    const ushort* __restrict__ gtb, const float* __restrict__ lgG,
    float* __restrict__ out)
{
    extern __shared__ char L[];
    float* wfl  = (float*)(L + 65536);
    float* wred = (float*)(L + 66048);

    const int bid   = blockIdx.x;
    const int t     = threadIdx.x;
    const int w     = t >> 6;
    const int lane  = t & 63;
    const int l15   = lane & 15;
    const int koff8 = (lane >> 4) * 8;
    const int koffb = koff8 * 2;

    const int b    = bid >> 3;
    const int sub  = bid & 7;
    const int term = sub >> 2;
    const int dq   = (sub >> 1) & 1;
    const int eo   = sub & 1;

    // ---- softmax (waves 0,1) ----
    float sv = 0.f, se = 0.f;
    if (t < 128) {
        sv = lgG[(size_t)(term * NB + b) * NL + t];
        float m = sv;
#pragma unroll
        for (int off = 1; off < 64; off <<= 1) m = fmaxf(m, __shfl_xor(m, off));
        if (lane == 0) wred[w] = m;
    }
    __syncthreads();
    if (t < 128) {
        float m = fmaxf(wred[0], wred[1]);
        se = expf(sv - m);
        float s = se;
#pragma unroll
        for (int off = 1; off < 64; off <<= 1) s += __shfl_xor(s, off);
        if (lane == 0) wred[2 + w] = s;
    }
    __syncthreads();
    if (t < 128) wfl[t] = se / (wred[2] + wred[3]);

    // ---- stage G of batch b (both arrays), swizzled ----
#pragma unroll
    for (int j = 0; j < 16; ++j) {
        int u    = t + 256 * j;
        int arr  = u >> 11;
        int row  = (u >> 4) & 127;
        int slot = u & 15;
        bf16x8 v = *(const bf16x8*)&gtb[((size_t)(arr * NB + b) * ND + row) * NL + slot * 8];
        *(bf16x8*)(L + arr * 32768 + row * 256 + ((slot * 16) ^ ((row & 7) << 4))) = v;
    }
    __syncthreads();   // covers staging AND wfl writes

    // ---- gram MFMA ----
    f32x4 accP[4], accN[4];
#pragma unroll
    for (int nt = 0; nt < 4; ++nt) {
        accP[nt] = (f32x4){0.f, 0.f, 0.f, 0.f};
        accN[nt] = (f32x4){0.f, 0.f, 0.f, 0.f};
    }

#pragma unroll
    for (int ks = 0; ks < 4; ++ks) {
        F4 w0, w1;
        w0.v = *(const float4*)&wfl[ks * 32 + koff8];
        w1.v = *(const float4*)&wfl[ks * 32 + koff8 + 4];
        float wv[8] = {w0.f[0], w0.f[1], w0.f[2], w0.f[3],
                       w1.f[0], w1.f[1], w1.f[2], w1.f[3]};

        const int ar = dq * 64 + w * 16 + l15;
        const int ab = ar * 256 + (((ks * 64) + koffb) ^ ((ar & 7) << 4));
        BF8 a0; a0.v = *(const bf16x8*)(L + ab);
        BF8 a1; a1.v = *(const bf16x8*)(L + 32768 + ab);
        bf16x8 s0, s1;
#pragma unroll
        for (int e = 0; e < 8; ++e) {
            s0[e] = (short)f2bf(bf2f(a0.u[e]) * wv[e]);
            s1[e] = (short)f2bf(bf2f(a1.u[e]) * wv[e]);
        }
        bf16x8 aP = term ? s1 : s0;   // R: wr.r2 ; I: wi.i2
        bf16x8 aN = term ? s0 : s1;   // R: wr.i2 ; I: wi.r2

#pragma unroll
        for (int nt = 0; nt < 4; ++nt) {
            const int br = eo * 64 + nt * 16 + l15;
            const int bb = br * 256 + (((ks * 64) + koffb) ^ ((br & 7) << 4));
            bf16x8 b0 = *(const bf16x8*)(L + bb);
            bf16x8 b1 = *(const bf16x8*)(L + 32768 + bb);
            accP[nt] = __builtin_amdgcn_mfma_f32_16x16x32_bf16(aP, b0, accP[nt], 0, 0, 0);
            accN[nt] = __builtin_amdgcn_mfma_f32_16x16x32_bf16(aN, b1, accN[nt], 0, 0, 0);
        }
    }

    const float sgn = term ? 1.f : -1.f;
    float* dst = out + (size_t)term * NB * ND * ND + (size_t)b * ND * ND;
    const int rb = dq * 64 + w * 16 + (lane >> 4) * 4;
#pragma unroll
    for (int nt = 0; nt < 4; ++nt) {
        const int ec = eo * 64 + nt * 16 + l15;
#pragma unroll
        for (int r = 0; r < 4; ++r)
            dst[(size_t)(rb + r) * ND + ec] = accP[nt][r] + sgn * accN[nt][r];
    }
}

extern "C" void kernel_launch(void* const* d_in, const int* in_sizes, int n_in,
                              void* d_out, int out_size, void* d_ws, size_t ws_size,
                              hipStream_t stream)
{
    const float* xr  = (const float*)d_in[0];
    const float* xi  = (const float*)d_in[1];
    const float* Wr1 = (const float*)d_in[2];
    const float* br1 = (const float*)d_in[3];
    const float* Wi1 = (const float*)d_in[4];
    const float* bi1 = (const float*)d_in[5];
    const float* Wr2 = (const float*)d_in[6];
    const float* br2 = (const float*)d_in[7];
    const float* Wi2 = (const float*)d_in[8];
    const float* bi2 = (const float*)d_in[9];

    ushort* gtb = (ushort*)d_ws;                     // [2][b][d][l] bf16
    float*  lgG = (float*)(gtb + 2 * NB * ND * NL);  // [2][b][l]

    (void)hipFuncSetAttribute((const void*)k_gram,
                              hipFuncAttributeMaxDynamicSharedMemorySize, 66560);

    hipLaunchKernelGGL(k_proj, dim3(256), dim3(256), 0, stream,
                       xr, xi, Wr1, br1, Wi1, bi1, Wr2, br2, Wi2, bi2,
                       gtb, lgG);
    hipLaunchKernelGGL(k_gram, dim3(256), dim3(256), 66560, stream,
                       gtb, lgG, (float*)d_out);
}